// Round 6
// baseline (286.700 us; speedup 1.0000x reference)
//
#include <hip/hip_runtime.h>
#include <hip/hip_fp16.h>

// Problem constants (fixed by reference)
#define M_TOTAL 25088          // 128*14*14 rows
#define KDIM    384
#define NDIM    1536
#define BMg     64
#define BNg     256
#define NKS     12             // 384 / 32 (MFMA K)

typedef __attribute__((ext_vector_type(8))) _Float16 half8;
typedef __attribute__((ext_vector_type(2))) _Float16 half2v;
typedef __attribute__((ext_vector_type(2))) float   f32x2;
typedef __attribute__((ext_vector_type(4))) float   f32x4;

#define GLOAD_LDS16(g, l)                                                     \
  __builtin_amdgcn_global_load_lds(                                           \
      (const __attribute__((address_space(1))) unsigned int*)(g),             \
      (__attribute__((address_space(3))) unsigned int*)(l), 16, 0, 0)

#if __has_builtin(__builtin_amdgcn_rcpf)
#define RCPF(v) __builtin_amdgcn_rcpf(v)
#else
#define RCPF(v) (1.0f / (v))
#endif

#define LN_BLOCKS (M_TOTAL / 4)            // 6272, 4 rows/block (1 wave each)
#define PW_BLOCKS 144                      // (384/64)*(1536/64) transpose tiles

// ---------------------------------------------------------------------------
// Kernel 1: LayerNorm->fp16 (blocks [0,6272)) + W->Bt LDS-tiled transpose
// (blocks [6272, 6272+144)).  Bt[f][c] = fp16(W[c][f]), Bt is [1536][384].
// ---------------------------------------------------------------------------
__global__ __launch_bounds__(256) void ln_prep(const float* __restrict__ x,
                                               const float* __restrict__ gamma,
                                               const float* __restrict__ beta,
                                               const float* __restrict__ W,
                                               _Float16* __restrict__ Ahi,
                                               _Float16* __restrict__ Bt) {
  __shared__ float T[64 * 65];             // transpose tile, +1 pad
  const int t = threadIdx.x;
  if (blockIdx.x >= LN_BLOCKS) {
    // ---- W transpose tile: 64 c x 64 f, coalesced read + contiguous write
    int b  = blockIdx.x - LN_BLOCKS;
    int c0 = (b % 6) * 64;
    int f0 = (b / 6) * 64;
    int fl = t & 63;
#pragma unroll
    for (int j = 0; j < 16; ++j) {
      int cl = (t >> 6) * 16 + j;
      T[fl * 65 + cl] = W[(size_t)(c0 + cl) * NDIM + f0 + fl];
    }
    __syncthreads();
    int fw = t >> 2;                       // 0..63 output f row
    int ch = t & 3;                        // 16-col chunk
    const float* src = &T[fw * 65 + ch * 16];
    half8 v0, v1;
#pragma unroll
    for (int i = 0; i < 8; ++i) { v0[i] = (_Float16)src[i]; v1[i] = (_Float16)src[8 + i]; }
    _Float16* dst = Bt + (size_t)(f0 + fw) * KDIM + c0 + ch * 16;
    *(half8*)dst       = v0;
    *(half8*)(dst + 8) = v1;
    return;
  }
  // ---- LayerNorm: one wave per row; lane owns col pairs {2*lane + 128*j}
  int wave = t >> 6;
  int lane = t & 63;
  int row  = blockIdx.x * 4 + wave;
  const float* xr = x + (size_t)row * KDIM;

  f32x2 v[3];
  float s = 0.f;
#pragma unroll
  for (int j = 0; j < 3; ++j) {
    v[j] = *(const f32x2*)(xr + 2 * lane + 128 * j);
    s += v[j].x + v[j].y;
  }
#pragma unroll
  for (int off = 32; off; off >>= 1) s += __shfl_xor(s, off);
  float mean = s * (1.f / 384.f);

  float s2 = 0.f;
#pragma unroll
  for (int j = 0; j < 3; ++j) {
    float dx = v[j].x - mean, dy = v[j].y - mean;
    s2 += dx * dx + dy * dy;
  }
#pragma unroll
  for (int off = 32; off; off >>= 1) s2 += __shfl_xor(s2, off);
  float rstd = rsqrtf(s2 * (1.f / 384.f) + 1e-5f);

  _Float16* hrow = Ahi + (size_t)row * KDIM;
#pragma unroll
  for (int j = 0; j < 3; ++j) {
    int c = 2 * lane + 128 * j;
    half2v h;
    h.x = (_Float16)((v[j].x - mean) * rstd * gamma[c] + beta[c]);
    h.y = (_Float16)((v[j].y - mean) * rstd * gamma[c + 1] + beta[c + 1]);
    *(half2v*)(hrow + c) = h;
  }
}

// ---------------------------------------------------------------------------
// Kernel 2: fp16 GEMM (M=25088, N=1536, K=384) + bias + GELU.
// NEW STRUCTURE (r6): full-K A-tile in LDS (64x384 = 48 KB), staged ONCE via
// gload_lds -> exactly ONE barrier per kernel. B frags stream from global
// (Bt is 1.18 MB, L2-resident; k-contiguous, imm-offset folded) into regs --
// no LDS for B, no per-step vmcnt(0) drain; compiler pipelines freely.
// 8 waves (2x4), wave tile 32x64, mfma_f32_16x16x32_f16, 96 MFMA/wave.
// A-LDS swizzle: 16B chunk c -> (c&~7)|((c&7)^(row&7)); bank grp = 4*xor,
// 2-way across 16 rows = free (m136). Inverse applied on global src (#21).
// Epilogue: stores ordered m,j,n-inner so both 64B halves of each 128B line
// issue back-to-back (kill r5's 31% write amplification). Fast A&S erf.
// ---------------------------------------------------------------------------
__global__ __launch_bounds__(512, 4) void gemm_fused(
    const _Float16* __restrict__ Ahi, const _Float16* __restrict__ Bt,
    const float* __restrict__ bias,   float* __restrict__ out) {
  __shared__ _Float16 Alds[BMg * KDIM];   // 48 KB

  const int tid  = threadIdx.x;
  const int lane = tid & 63;
  const int wave = tid >> 6;
  const int wr   = wave >> 2;          // 0..1  (row half)
  const int wc   = wave & 3;           // 0..3  (col quarter)

  // XCD-aware bijective swizzle: nwg = 392*6 = 2352 = 8*294; nb fastest so
  // same-mb blocks are XCD-adjacent -> A-tile L2 reuse across nb.
  int bidx = blockIdx.x;
  int swz  = (bidx & 7) * 294 + (bidx >> 3);
  int mb   = swz / 6;
  int nb   = swz - mb * 6;
  const int mrow0 = mb * BMg;
  const int ncol0 = nb * BNg;

  // --- A staging: 48 instrs (6/wave), 1 KB each; LDS linear dest,
  //     inverse-swizzled global source.
  const _Float16* asrc[6];
#pragma unroll
  for (int ii = 0; ii < 6; ++ii) {
    int L   = (wave * 6 + ii) * 1024 + lane * 16;   // LDS byte addr
    int r   = L / 768;                              // tile row 0..63
    int cs  = (L - r * 768) >> 4;                   // swizzled chunk 0..47
    int c   = (cs & ~7) | ((cs & 7) ^ (r & 7));     // global chunk
    asrc[ii] = Ahi + (size_t)(mrow0 + r) * KDIM + c * 8;
  }
#pragma unroll
  for (int ii = 0; ii < 6; ++ii)
    GLOAD_LDS16(asrc[ii], &Alds[(wave * 6 + ii) * 512]);

  // --- B fragment base pointers (global, k-contiguous; +32 halves per ks
  //     folds into the load's immediate offset) ---
  const _Float16* bptr[4];
#pragma unroll
  for (int n = 0; n < 4; ++n)
    bptr[n] = Bt + (size_t)(ncol0 + wc * 64 + n * 16 + (lane & 15)) * KDIM +
              (lane >> 4) * 8;

  // --- A fragment read offsets (half-index): row = wr*32+m*16+(lane&15),
  //     addr = row*384 + 64*(ks>>1) + 8*((4*(ks&1)+g)^(row&7)), g=lane>>4.
  const int g = lane >> 4;
  int e0[2], e1[2];
#pragma unroll
  for (int m = 0; m < 2; ++m) {
    int r  = wr * 32 + m * 16 + (lane & 15);
    e0[m] = r * KDIM + 8 * (g ^ (r & 7));
    e1[m] = r * KDIM + 8 * ((4 + g) ^ (r & 7));
  }

  f32x4 acc[2][4];
#pragma unroll
  for (int m = 0; m < 2; ++m)
#pragma unroll
    for (int n = 0; n < 4; ++n) acc[m][n] = (f32x4){0.f, 0.f, 0.f, 0.f};

  __syncthreads();                       // the ONLY barrier: A-tile ready

  // --- K loop: 12 unrolled steps; no barriers, loads pipeline freely ---
#pragma unroll
  for (int ks = 0; ks < NKS; ++ks) {
    half8 bf[4];
#pragma unroll
    for (int n = 0; n < 4; ++n)
      bf[n] = *(const half8*)(bptr[n] + ks * 32);
    half8 af[2];
#pragma unroll
    for (int m = 0; m < 2; ++m) {
      int e = ((ks & 1) ? e1[m] : e0[m]) + 64 * (ks >> 1);
      af[m] = *(const half8*)&Alds[e];
    }
#pragma unroll
    for (int m = 0; m < 2; ++m)
#pragma unroll
      for (int n = 0; n < 4; ++n)
        acc[m][n] = __builtin_amdgcn_mfma_f32_16x16x32_f16(
            af[m], bf[n], acc[m][n], 0, 0, 0);
  }

  // --- epilogue: bias + GELU (A&S 7.1.26 erf), n-inner store order ---
  float bv[4];
#pragma unroll
  for (int n = 0; n < 4; ++n)
    bv[n] = bias[ncol0 + wc * 64 + n * 16 + (lane & 15)];

#pragma unroll
  for (int m = 0; m < 2; ++m) {
#pragma unroll
    for (int j = 0; j < 4; ++j) {
      int row = mrow0 + wr * 32 + m * 16 + ((lane >> 4) << 2) + j;
      float* orow = out + (size_t)row * NDIM + ncol0 + wc * 64 + (lane & 15);
#pragma unroll
      for (int n = 0; n < 4; ++n) {      // n-inner: 64B halves back-to-back
        float y  = acc[m][n][j] + bv[n];
        float ay = fabsf(y);
        float xe = ay * 0.70710678118654752f;
        float tt = RCPF(1.0f + 0.3275911f * xe);
        float p  = ((((1.061405429f * tt - 1.453152027f) * tt + 1.421413741f) *
                         tt - 0.284496736f) * tt + 0.254829592f) * tt;
        float e  = 1.0f - p * __expf(-xe * xe);
        orow[n * 16] = 0.5f * (y + ay * e);
      }
    }
  }
}

// ---------------------------------------------------------------------------
extern "C" void kernel_launch(void* const* d_in, const int* in_sizes, int n_in,
                              void* d_out, int out_size, void* d_ws, size_t ws_size,
                              hipStream_t stream) {
  const float* x     = (const float*)d_in[0];
  const float* gamma = (const float*)d_in[1];
  const float* beta  = (const float*)d_in[2];
  const float* W     = (const float*)d_in[3];
  const float* bias  = (const float*)d_in[4];
  float* out = (float*)d_out;

  _Float16* Ahi = (_Float16*)d_ws;                                  // 19.27 MB
  _Float16* Btd = (_Float16*)((char*)d_ws + (size_t)M_TOTAL * KDIM * 2);

  hipLaunchKernelGGL(ln_prep, dim3(LN_BLOCKS + PW_BLOCKS), dim3(256), 0,
                     stream, x, gamma, beta, W, Ahi, Btd);
  hipLaunchKernelGGL(gemm_fused, dim3((M_TOTAL / BMg) * (NDIM / BNg)),
                     dim3(512), 0, stream, Ahi, Btd, bias, out);
}